// Round 4
// baseline (690.301 us; speedup 1.0000x reference)
//
#include <hip/hip_runtime.h>
#include <hip/hip_bf16.h>
#include <math.h>

typedef __attribute__((ext_vector_type(8))) short short8;
typedef __attribute__((ext_vector_type(4))) float f32x4;

#define MFMA_BF16 __builtin_amdgcn_mfma_f32_16x16x32_bf16

__device__ __forceinline__ ushort f2bf(float f) {
  union { __hip_bfloat16 h; ushort u; } c;
  c.h = __float2bfloat16(f);
  return c.u;
}
// round-half-up bf16 pack (positive normal floats): 5 VALU ops per pair
__device__ __forceinline__ uint pack_bf16_ru(float a, float b) {
  uint ua = __builtin_bit_cast(uint, a) + 0x8000u;
  uint ub = __builtin_bit_cast(uint, b) + 0x8000u;
  return (ua >> 16) | (ub & 0xffff0000u);
}
__device__ __forceinline__ void async_cp16(const ushort* g, ushort* l) {
  __builtin_amdgcn_global_load_lds(
      (const __attribute__((address_space(1))) void*)g,
      (__attribute__((address_space(3))) void*)l, 16, 0, 0);
}

// ---------------- weight fp32 -> bf16 ----------------
__global__ __launch_bounds__(256) void conv_bf16(const float* __restrict__ src,
                                                 ushort* __restrict__ dst, int n4) {
  int i = blockIdx.x * 256 + threadIdx.x;
  if (i < n4) {
    float4 v = ((const float4*)src)[i];
    ushort4 o;
    o.x = f2bf(v.x); o.y = f2bf(v.y); o.z = f2bf(v.z); o.w = f2bf(v.w);
    ((ushort4*)dst)[i] = o;
  }
}

// ---------------- layernorm: one block per 1024-float row -> bf16 ----------------
__global__ __launch_bounds__(256) void ln_kernel(const float* __restrict__ x,
    const float* __restrict__ g, const float* __restrict__ b,
    ushort* __restrict__ out) {
  const int row = blockIdx.x, t = threadIdx.x;
  float4 v = ((const float4*)(x + (size_t)row * 1024))[t];
  float s  = v.x + v.y + v.z + v.w;
  float ss = v.x*v.x + v.y*v.y + v.z*v.z + v.w*v.w;
  #pragma unroll
  for (int off = 32; off >= 1; off >>= 1) {
    s  += __shfl_xor(s, off);
    ss += __shfl_xor(ss, off);
  }
  __shared__ float red[8];
  int wv = t >> 6, ln = t & 63;
  if (ln == 0) { red[wv] = s; red[4 + wv] = ss; }
  __syncthreads();
  float S  = red[0] + red[1] + red[2] + red[3];
  float SS = red[4] + red[5] + red[6] + red[7];
  float mu  = S * (1.0f/1024.0f);
  float var = SS * (1.0f/1024.0f) - mu*mu;
  float rs  = rsqrtf(var + 1e-6f);
  float4 gv = ((const float4*)g)[t];
  float4 bv = ((const float4*)b)[t];
  ushort4 o;
  o.x = f2bf((v.x-mu)*rs*gv.x + bv.x);
  o.y = f2bf((v.y-mu)*rs*gv.y + bv.y);
  o.z = f2bf((v.z-mu)*rs*gv.z + bv.z);
  o.w = f2bf((v.w-mu)*rs*gv.w + bv.w);
  ((ushort4*)(out + (size_t)row*1024))[t] = o;
}

// ---------------- tiled bf16 GEMM, BK=64: C[m,n] = sum_k A[m,k]*W[n,k] ----------------
// 128x128 tile, 4 waves. BK=64 as two side-by-side stride-64B sub-tiles (keeps the
// proven global_load_lds lane mapping). 32 MFMAs per wave per barrier-pair.
enum { EPI_QK = 0, EPI_V = 1, EPI_WO = 2, EPI_GELU = 3, EPI_OUT = 4 };

template <int EPI>
__global__ __launch_bounds__(256) void gemm_kernel(const ushort* __restrict__ A,
    const ushort* __restrict__ Bw, const float* __restrict__ bias,
    const float* __restrict__ res, void* __restrict__ outp, int K, int N,
    float scale) {
  __shared__ ushort As[2][128 * 32];   // [k-chunk][row*32+col] unpadded
  __shared__ ushort Bs[2][128 * 32];
  const int t = threadIdx.x;
  const int m0 = blockIdx.x * 128, n0 = blockIdx.y * 128;
  const int lane = t & 63, wave = t >> 6;
  const int col = lane & 15, quad = lane >> 4;
  const int wrow = (wave >> 1) * 64, wcol = (wave & 1) * 64;

  f32x4 acc[4][4];
  #pragma unroll
  for (int i = 0; i < 4; i++)
    #pragma unroll
    for (int j = 0; j < 4; j++)
      acc[i][j] = (f32x4){0.f, 0.f, 0.f, 0.f};

  const int lrow = lane >> 2, lcol = (lane & 3) * 8;
  const ushort* Ag = A  + (size_t)(m0 + wave * 32 + lrow) * K + lcol;
  const ushort* Bg = Bw + (size_t)(n0 + wave * 32 + lrow) * K + lcol;
  const int ldso = (wave * 32) * 32;

  for (int k0 = 0; k0 < K; k0 += 64) {
    __syncthreads();
    #pragma unroll
    for (int c = 0; c < 2; c++) {
      async_cp16(Ag + k0 + c * 32,                  &As[c][ldso]);
      async_cp16(Ag + (size_t)16 * K + k0 + c * 32, &As[c][ldso + 16 * 32]);
      async_cp16(Bg + k0 + c * 32,                  &Bs[c][ldso]);
      async_cp16(Bg + (size_t)16 * K + k0 + c * 32, &Bs[c][ldso + 16 * 32]);
    }
    __syncthreads();
    #pragma unroll
    for (int c = 0; c < 2; c++) {
      short8 af[4], bf[4];
      #pragma unroll
      for (int tm = 0; tm < 4; tm++)
        af[tm] = *(const short8*)&As[c][(wrow + tm * 16 + col) * 32 + quad * 8];
      #pragma unroll
      for (int tn = 0; tn < 4; tn++)
        bf[tn] = *(const short8*)&Bs[c][(wcol + tn * 16 + col) * 32 + quad * 8];
      #pragma unroll
      for (int tm = 0; tm < 4; tm++)
        #pragma unroll
        for (int tn = 0; tn < 4; tn++)
          acc[tm][tn] = MFMA_BF16(af[tm], bf[tn], acc[tm][tn], 0, 0, 0);
    }
  }

  #pragma unroll
  for (int tm = 0; tm < 4; tm++) {
    #pragma unroll
    for (int tn = 0; tn < 4; tn++) {
      const int n = n0 + wcol + tn * 16 + col;
      const float bn = bias[n];
      #pragma unroll
      for (int r = 0; r < 4; r++) {
        const int m = m0 + wrow + tm * 16 + quad * 4 + r;
        float v = acc[tm][tn][r] + bn;
        if (EPI == EPI_QK) {
          int bb = m >> 11, s2 = m & 2047, h = n >> 6, hd = n & 63;
          ((ushort*)outp)[(((size_t)(bb * 16 + h) * 2048 + s2) * 64) + hd] = f2bf(v * scale);
        } else if (EPI == EPI_V) {
          int bb = m >> 11, s2 = m & 2047, h = n >> 6, hd = n & 63;
          ((ushort*)outp)[(((size_t)(bb * 16 + h) * 64 + hd) * 2048) + s2] = f2bf(v);
        } else if (EPI == EPI_WO) {
          ((float*)outp)[(size_t)m * N + n] = v + res[(size_t)m * N + n];
        } else if (EPI == EPI_GELU) {
          float u = v * 0.7978845608028654f * (1.0f + 0.044715f * v * v);
          float e = __builtin_amdgcn_exp2f(u * 2.885390081777927f);  // e^{2u}
          float th = 1.0f - 2.0f * __builtin_amdgcn_rcpf(e + 1.0f);
          ((ushort*)outp)[(size_t)m * N + n] = f2bf(0.5f * v * (1.0f + th));
        } else {  // EPI_OUT
          ((float*)outp)[(size_t)m * N + n] = v + res[(size_t)m * N + n];
        }
      }
    }
  }
}

// ---------------- flash attention v4 ----------------
// Q: [BH,S,64] bf16 PRE-SCALED by log2(e)/8. K: [BH,S,64]. Vt: [BH,64,S].
// Grid: 1024 blocks = 64 heads x 16 q-tiles(128). 4 waves; wave owns 32 q (2 groups).
// XCD-clustered: head=(bx&7)*8+((bx>>3)&7) -> 8 heads/XCD = 4MB K/V = L2-resident.
// Scores transposed (C cols = q); per-lane softmax denom; no max subtraction.
__global__ __launch_bounds__(256) void attn_kernel(const ushort* __restrict__ Qb,
    const ushort* __restrict__ Kb, const ushort* __restrict__ Vt,
    ushort* __restrict__ ctx) {
  const int lane = threadIdx.x & 63, wave = threadIdx.x >> 6;
  const int col = lane & 15, quad = lane >> 4;
  const int bx = blockIdx.x;
  const int bh = (bx & 7) * 8 + ((bx >> 3) & 7);
  const int qt = bx >> 6;
  const int qbase = qt * 128 + wave * 32;
  const ushort* Qh = Qb + (size_t)bh * 2048 * 64;
  const ushort* Kh = Kb + (size_t)bh * 2048 * 64;
  const ushort* Vh = Vt + (size_t)bh * 64 * 2048;

  short8 qa[2][2];
  #pragma unroll
  for (int qg = 0; qg < 2; qg++) {
    const ushort* Qr = Qh + (size_t)(qbase + qg * 16 + col) * 64 + quad * 8;
    qa[qg][0] = *(const short8*)Qr;
    qa[qg][1] = *(const short8*)(Qr + 32);
  }

  f32x4 Ot[2][4];              // [qg][dt]: O^T, lane q=col, d = dt*16+quad*4+r
  float l_part[2];
  #pragma unroll
  for (int qg = 0; qg < 2; qg++) {
    l_part[qg] = 0.f;
    #pragma unroll
    for (int dt = 0; dt < 4; dt++) Ot[qg][dt] = (f32x4){0.f, 0.f, 0.f, 0.f};
  }

  __shared__ ushort P_lds[4][2][16][40];   // [wave][qg][q][key], 80B row stride
  const ushort* Kc = Kh + (size_t)col * 64 + quad * 8;
  const ushort* Vc = Vh + (size_t)col * 2048 + quad * 8;

  for (int kb = 0; kb < 2048; kb += 32) {
    short8 kf[2][2];
    #pragma unroll
    for (int kt = 0; kt < 2; kt++) {
      const ushort* Kr = Kc + (size_t)(kb + kt * 16) * 64;
      kf[kt][0] = *(const short8*)Kr;
      kf[kt][1] = *(const short8*)(Kr + 32);
    }
    short8 vf[4];
    #pragma unroll
    for (int dt = 0; dt < 4; dt++)
      vf[dt] = *(const short8*)(Vc + (size_t)dt * 16 * 2048 + kb);

    #pragma unroll
    for (int qg = 0; qg < 2; qg++) {
      f32x4 s0 = (f32x4){0.f, 0.f, 0.f, 0.f};
      f32x4 s1 = (f32x4){0.f, 0.f, 0.f, 0.f};
      s0 = MFMA_BF16(kf[0][0], qa[qg][0], s0, 0, 0, 0);
      s0 = MFMA_BF16(kf[0][1], qa[qg][1], s0, 0, 0, 0);
      s1 = MFMA_BF16(kf[1][0], qa[qg][0], s1, 0, 0, 0);
      s1 = MFMA_BF16(kf[1][1], qa[qg][1], s1, 0, 0, 0);
      // scale already folded into Q: p = exp2(s)
      float p0 = __builtin_amdgcn_exp2f(s0[0]);
      float p1 = __builtin_amdgcn_exp2f(s0[1]);
      float p2 = __builtin_amdgcn_exp2f(s0[2]);
      float p3 = __builtin_amdgcn_exp2f(s0[3]);
      float p4 = __builtin_amdgcn_exp2f(s1[0]);
      float p5 = __builtin_amdgcn_exp2f(s1[1]);
      float p6 = __builtin_amdgcn_exp2f(s1[2]);
      float p7 = __builtin_amdgcn_exp2f(s1[3]);
      l_part[qg] += (p0 + p1) + (p2 + p3) + (p4 + p5) + (p6 + p7);
      ushort(*P)[40] = P_lds[wave][qg];
      *(uint*)&P[col][quad * 4]          = pack_bf16_ru(p0, p1);
      *(uint*)&P[col][quad * 4 + 2]      = pack_bf16_ru(p2, p3);
      *(uint*)&P[col][16 + quad * 4]     = pack_bf16_ru(p4, p5);
      *(uint*)&P[col][16 + quad * 4 + 2] = pack_bf16_ru(p6, p7);
    }
    #pragma unroll
    for (int qg = 0; qg < 2; qg++) {
      short8 pf = *(const short8*)&P_lds[wave][qg][col][quad * 8];
      #pragma unroll
      for (int dt = 0; dt < 4; dt++)
        Ot[qg][dt] = MFMA_BF16(vf[dt], pf, Ot[qg][dt], 0, 0, 0);
    }
  }

  const int bb = bh >> 4, h = bh & 15;
  #pragma unroll
  for (int qg = 0; qg < 2; qg++) {
    float l = l_part[qg];
    l += __shfl_xor(l, 16);
    l += __shfl_xor(l, 32);
    float inv = __builtin_amdgcn_rcpf(l);
    const int q = qbase + qg * 16 + col;
    size_t base = ((size_t)(bb * 2048 + q)) * 1024 + h * 64;
    #pragma unroll
    for (int dt = 0; dt < 4; dt++) {
      ushort4 o;
      o.x = f2bf(Ot[qg][dt][0] * inv);
      o.y = f2bf(Ot[qg][dt][1] * inv);
      o.z = f2bf(Ot[qg][dt][2] * inv);
      o.w = f2bf(Ot[qg][dt][3] * inv);
      *(ushort4*)&ctx[base + dt * 16 + quad * 4] = o;
    }
  }
}

// ---------------- host ----------------
extern "C" void kernel_launch(void* const* d_in, const int* in_sizes, int n_in,
                              void* d_out, int out_size, void* d_ws, size_t ws_size,
                              hipStream_t stream) {
  const float* x     = (const float*)d_in[0];
  const float* Wq    = (const float*)d_in[1];
  const float* bq    = (const float*)d_in[2];
  const float* Wk    = (const float*)d_in[3];
  const float* bk    = (const float*)d_in[4];
  const float* Wv    = (const float*)d_in[5];
  const float* bv    = (const float*)d_in[6];
  const float* Wo    = (const float*)d_in[7];
  const float* bo    = (const float*)d_in[8];
  const float* W1    = (const float*)d_in[9];
  const float* b1    = (const float*)d_in[10];
  const float* W2    = (const float*)d_in[11];
  const float* b2    = (const float*)d_in[12];
  const float* ln1_g = (const float*)d_in[13];
  const float* ln1_b = (const float*)d_in[14];
  const float* ln2_g = (const float*)d_in[15];
  const float* ln2_b = (const float*)d_in[16];

  const size_t MB = 1ull << 20;
  char* ws = (char*)d_ws;
  ushort* Wq_b = (ushort*)(ws + 0 * MB);
  ushort* Wk_b = (ushort*)(ws + 2 * MB);
  ushort* Wv_b = (ushort*)(ws + 4 * MB);
  ushort* Wo_b = (ushort*)(ws + 6 * MB);
  ushort* W1_b = (ushort*)(ws + 8 * MB);
  ushort* W2_b = (ushort*)(ws + 16 * MB);
  ushort* xn1  = (ushort*)(ws + 24 * MB);
  ushort* Qb   = (ushort*)(ws + 40 * MB);
  ushort* Kb   = (ushort*)(ws + 56 * MB);
  ushort* Vt   = (ushort*)(ws + 72 * MB);
  ushort* ctxb = (ushort*)(ws + 88 * MB);
  float*  x2   = (float*)(ws + 104 * MB);
  ushort* xn2  = (ushort*)(ws + 136 * MB);
  ushort* y1   = (ushort*)(ws + 152 * MB);

  conv_bf16<<<1024, 256, 0, stream>>>(Wq, Wq_b, 262144);
  conv_bf16<<<1024, 256, 0, stream>>>(Wk, Wk_b, 262144);
  conv_bf16<<<1024, 256, 0, stream>>>(Wv, Wv_b, 262144);
  conv_bf16<<<1024, 256, 0, stream>>>(Wo, Wo_b, 262144);
  conv_bf16<<<4096, 256, 0, stream>>>(W1, W1_b, 1048576);
  conv_bf16<<<4096, 256, 0, stream>>>(W2, W2_b, 1048576);

  ln_kernel<<<8192, 256, 0, stream>>>(x, ln1_g, ln1_b, xn1);

  const float cs = 0.125f * 1.4426950408889634f;  // log2(e)/sqrt(64), folded into Q
  gemm_kernel<EPI_QK><<<dim3(64, 8), 256, 0, stream>>>(xn1, Wq_b, bq, nullptr, Qb, 1024, 1024, cs);
  gemm_kernel<EPI_QK><<<dim3(64, 8), 256, 0, stream>>>(xn1, Wk_b, bk, nullptr, Kb, 1024, 1024, 1.0f);
  gemm_kernel<EPI_V ><<<dim3(64, 8), 256, 0, stream>>>(xn1, Wv_b, bv, nullptr, Vt, 1024, 1024, 1.0f);

  attn_kernel<<<1024, 256, 0, stream>>>(Qb, Kb, Vt, ctxb);

  gemm_kernel<EPI_WO><<<dim3(64, 8), 256, 0, stream>>>(ctxb, Wo_b, bo, x, x2, 1024, 1024, 1.0f);

  ln_kernel<<<8192, 256, 0, stream>>>(x2, ln2_g, ln2_b, xn2);

  gemm_kernel<EPI_GELU><<<dim3(64, 32), 256, 0, stream>>>(xn2, W1_b, b1, nullptr, y1, 1024, 4096, 1.0f);
  gemm_kernel<EPI_OUT ><<<dim3(64, 8), 256, 0, stream>>>(y1, W2_b, b2, x2, d_out, 4096, 1024, 1.0f);
}

// Round 5
// 580.980 us; speedup vs baseline: 1.1882x; 1.1882x over previous
//
#include <hip/hip_runtime.h>
#include <hip/hip_bf16.h>
#include <math.h>

typedef __attribute__((ext_vector_type(8))) short short8;
typedef __attribute__((ext_vector_type(4))) float f32x4;

#define MFMA_BF16 __builtin_amdgcn_mfma_f32_16x16x32_bf16

__device__ __forceinline__ ushort f2bf(float f) {
  union { __hip_bfloat16 h; ushort u; } c;
  c.h = __float2bfloat16(f);
  return c.u;
}
// round-half-up bf16 pack (positive normal floats): 5 VALU ops per pair
__device__ __forceinline__ uint pack_bf16_ru(float a, float b) {
  uint ua = __builtin_bit_cast(uint, a) + 0x8000u;
  uint ub = __builtin_bit_cast(uint, b) + 0x8000u;
  return (ua >> 16) | (ub & 0xffff0000u);
}
__device__ __forceinline__ void async_cp16(const ushort* g, ushort* l) {
  __builtin_amdgcn_global_load_lds(
      (const __attribute__((address_space(1))) void*)g,
      (__attribute__((address_space(3))) void*)l, 16, 0, 0);
}

// ------------- fused weight fp32->bf16 conversion + bias concat (one launch) -------------
__global__ __launch_bounds__(256) void conv_all(
    const float* __restrict__ Wq, const float* __restrict__ Wk,
    const float* __restrict__ Wv, const float* __restrict__ Wo,
    const float* __restrict__ W1, const float* __restrict__ W2,
    const float* __restrict__ bq, const float* __restrict__ bk,
    const float* __restrict__ bv,
    ushort* __restrict__ wqkv, ushort* __restrict__ wo,
    ushort* __restrict__ w1, ushort* __restrict__ w2,
    float* __restrict__ bqkv) {
  int i = blockIdx.x * 256 + threadIdx.x;   // float4 index
  if (i < 3145728) {
    const float* src; ushort* dst; int off;
    if (i < 786432)        { // Wq|Wk|Wv -> concatenated wqkv [3072,1024]
      dst = wqkv; off = i;
      if (i < 262144)      src = Wq + (size_t)i * 4;
      else if (i < 524288) src = Wk + (size_t)(i - 262144) * 4;
      else                 src = Wv + (size_t)(i - 524288) * 4;
    } else if (i < 1048576) { dst = wo; off = i - 786432;  src = Wo + (size_t)off * 4; }
    else if (i < 2097152)   { dst = w1; off = i - 1048576; src = W1 + (size_t)off * 4; }
    else                    { dst = w2; off = i - 2097152; src = W2 + (size_t)off * 4; }
    float4 v = *(const float4*)src;
    ushort4 o;
    o.x = f2bf(v.x); o.y = f2bf(v.y); o.z = f2bf(v.z); o.w = f2bf(v.w);
    ((ushort4*)dst)[off] = o;
  } else if (i < 3146496) {  // biases: 3 x 256 float4
    int off = i - 3145728;
    const float* src;
    if (off < 256)      src = bq + (size_t)off * 4;
    else if (off < 512) src = bk + (size_t)(off - 256) * 4;
    else                src = bv + (size_t)(off - 512) * 4;
    ((float4*)bqkv)[off] = *(const float4*)src;
  }
}

// ---------------- layernorm: one block per 1024-float row -> bf16 ----------------
__global__ __launch_bounds__(256) void ln_kernel(const float* __restrict__ x,
    const float* __restrict__ g, const float* __restrict__ b,
    ushort* __restrict__ out) {
  const int row = blockIdx.x, t = threadIdx.x;
  float4 v = ((const float4*)(x + (size_t)row * 1024))[t];
  float s  = v.x + v.y + v.z + v.w;
  float ss = v.x*v.x + v.y*v.y + v.z*v.z + v.w*v.w;
  #pragma unroll
  for (int off = 32; off >= 1; off >>= 1) {
    s  += __shfl_xor(s, off);
    ss += __shfl_xor(ss, off);
  }
  __shared__ float red[8];
  int wv = t >> 6, ln = t & 63;
  if (ln == 0) { red[wv] = s; red[4 + wv] = ss; }
  __syncthreads();
  float S  = red[0] + red[1] + red[2] + red[3];
  float SS = red[4] + red[5] + red[6] + red[7];
  float mu  = S * (1.0f/1024.0f);
  float var = SS * (1.0f/1024.0f) - mu*mu;
  float rs  = rsqrtf(var + 1e-6f);
  float4 gv = ((const float4*)g)[t];
  float4 bv = ((const float4*)b)[t];
  ushort4 o;
  o.x = f2bf((v.x-mu)*rs*gv.x + bv.x);
  o.y = f2bf((v.y-mu)*rs*gv.y + bv.y);
  o.z = f2bf((v.z-mu)*rs*gv.z + bv.z);
  o.w = f2bf((v.w-mu)*rs*gv.w + bv.w);
  ((ushort4*)(out + (size_t)row*1024))[t] = o;
}

// ---------------- tiled bf16 GEMM, BK=64: C[m,n] = sum_k A[m,k]*W[n,k] ----------------
// 128x128 tile, 4 waves. BK=64 as two side-by-side stride-64B sub-tiles (keeps the
// proven global_load_lds lane mapping). 32 MFMAs per wave per barrier-pair.
enum { EPI_QKV = 0, EPI_WO = 2, EPI_GELU = 3, EPI_OUT = 4 };

template <int EPI>
__global__ __launch_bounds__(256) void gemm_kernel(const ushort* __restrict__ A,
    const ushort* __restrict__ Bw, const float* __restrict__ bias,
    const float* __restrict__ res, void* __restrict__ outp,
    void* __restrict__ outp2, void* __restrict__ outp3, int K, int N,
    float scale) {
  __shared__ ushort As[2][128 * 32];   // [k-chunk][row*32+col] unpadded
  __shared__ ushort Bs[2][128 * 32];
  const int t = threadIdx.x;
  const int m0 = blockIdx.x * 128, n0 = blockIdx.y * 128;
  const int lane = t & 63, wave = t >> 6;
  const int col = lane & 15, quad = lane >> 4;
  const int wrow = (wave >> 1) * 64, wcol = (wave & 1) * 64;

  f32x4 acc[4][4];
  #pragma unroll
  for (int i = 0; i < 4; i++)
    #pragma unroll
    for (int j = 0; j < 4; j++)
      acc[i][j] = (f32x4){0.f, 0.f, 0.f, 0.f};

  const int lrow = lane >> 2, lcol = (lane & 3) * 8;
  const ushort* Ag = A  + (size_t)(m0 + wave * 32 + lrow) * K + lcol;
  const ushort* Bg = Bw + (size_t)(n0 + wave * 32 + lrow) * K + lcol;
  const int ldso = (wave * 32) * 32;

  for (int k0 = 0; k0 < K; k0 += 64) {
    __syncthreads();
    #pragma unroll
    for (int c = 0; c < 2; c++) {
      async_cp16(Ag + k0 + c * 32,                  &As[c][ldso]);
      async_cp16(Ag + (size_t)16 * K + k0 + c * 32, &As[c][ldso + 16 * 32]);
      async_cp16(Bg + k0 + c * 32,                  &Bs[c][ldso]);
      async_cp16(Bg + (size_t)16 * K + k0 + c * 32, &Bs[c][ldso + 16 * 32]);
    }
    __syncthreads();
    #pragma unroll
    for (int c = 0; c < 2; c++) {
      short8 af[4], bf[4];
      #pragma unroll
      for (int tm = 0; tm < 4; tm++)
        af[tm] = *(const short8*)&As[c][(wrow + tm * 16 + col) * 32 + quad * 8];
      #pragma unroll
      for (int tn = 0; tn < 4; tn++)
        bf[tn] = *(const short8*)&Bs[c][(wcol + tn * 16 + col) * 32 + quad * 8];
      #pragma unroll
      for (int tm = 0; tm < 4; tm++)
        #pragma unroll
        for (int tn = 0; tn < 4; tn++)
          acc[tm][tn] = MFMA_BF16(af[tm], bf[tn], acc[tm][tn], 0, 0, 0);
    }
  }

  #pragma unroll
  for (int tm = 0; tm < 4; tm++) {
    #pragma unroll
    for (int tn = 0; tn < 4; tn++) {
      const int n = n0 + wcol + tn * 16 + col;
      const float bn = bias[n];
      #pragma unroll
      for (int r = 0; r < 4; r++) {
        const int m = m0 + wrow + tm * 16 + quad * 4 + r;
        float v = acc[tm][tn][r] + bn;
        if (EPI == EPI_QKV) {
          // n in [0,3072): 0..1023 -> Q (scaled), 1024..2047 -> K, 2048.. -> V^T
          int which = n >> 10;
          int nl = n & 1023, h = nl >> 6, hd = nl & 63;
          int bb = m >> 11, s2 = m & 2047;
          if (which == 0)
            ((ushort*)outp)[(((size_t)(bb * 16 + h) * 2048 + s2) * 64) + hd] = f2bf(v * scale);
          else if (which == 1)
            ((ushort*)outp2)[(((size_t)(bb * 16 + h) * 2048 + s2) * 64) + hd] = f2bf(v);
          else
            ((ushort*)outp3)[(((size_t)(bb * 16 + h) * 64 + hd) * 2048) + s2] = f2bf(v);
        } else if (EPI == EPI_WO) {
          ((float*)outp)[(size_t)m * N + n] = v + res[(size_t)m * N + n];
        } else if (EPI == EPI_GELU) {
          float u = v * 0.7978845608028654f * (1.0f + 0.044715f * v * v);
          float e = __builtin_amdgcn_exp2f(u * 2.885390081777927f);  // e^{2u}
          float th = 1.0f - 2.0f * __builtin_amdgcn_rcpf(e + 1.0f);
          ((ushort*)outp)[(size_t)m * N + n] = f2bf(0.5f * v * (1.0f + th));
        } else {  // EPI_OUT
          ((float*)outp)[(size_t)m * N + n] = v + res[(size_t)m * N + n];
        }
      }
    }
  }
}

// ---------------- flash attention v5 ----------------
// Q: [BH,S,64] bf16 PRE-SCALED by log2(e)/8. K: [BH,S,64]. Vt: [BH,64,S].
// Grid: 512 blocks = 64 heads x 8 q-tiles(256). 4 waves; wave owns 64 q (4 groups).
// XCD-clustered: head=(bx&7)*8+((bx>>3)&7) -> 8 heads/XCD = 4MB K/V = L2-resident.
// Register prefetch of next kb's K/V fragments hides L2 latency one iter deep.
__global__ __launch_bounds__(256) void attn_kernel(const ushort* __restrict__ Qb,
    const ushort* __restrict__ Kb, const ushort* __restrict__ Vt,
    ushort* __restrict__ ctx) {
  const int lane = threadIdx.x & 63, wave = threadIdx.x >> 6;
  const int col = lane & 15, quad = lane >> 4;
  const int bx = blockIdx.x;
  const int bh = (bx & 7) * 8 + ((bx >> 3) & 7);
  const int qt = bx >> 6;
  const int qbase = qt * 256 + wave * 64;
  const ushort* Qh = Qb + (size_t)bh * 2048 * 64;
  const ushort* Kh = Kb + (size_t)bh * 2048 * 64;
  const ushort* Vh = Vt + (size_t)bh * 64 * 2048;

  short8 qa[4][2];
  #pragma unroll
  for (int qg = 0; qg < 4; qg++) {
    const ushort* Qr = Qh + (size_t)(qbase + qg * 16 + col) * 64 + quad * 8;
    qa[qg][0] = *(const short8*)Qr;
    qa[qg][1] = *(const short8*)(Qr + 32);
  }

  f32x4 Ot[4][4];              // [qg][dt]: O^T, lane q=col, d = dt*16+quad*4+r
  float l_part[4];
  #pragma unroll
  for (int qg = 0; qg < 4; qg++) {
    l_part[qg] = 0.f;
    #pragma unroll
    for (int dt = 0; dt < 4; dt++) Ot[qg][dt] = (f32x4){0.f, 0.f, 0.f, 0.f};
  }

  __shared__ ushort P_lds[4][4][16][40];   // [wave][qg][q][key], 80B row stride
  const ushort* Kc = Kh + (size_t)col * 64 + quad * 8;
  const ushort* Vc = Vh + (size_t)col * 2048 + quad * 8;

  // preload kb=0 fragments
  short8 kf[2][2], vf[4];
  #pragma unroll
  for (int kt = 0; kt < 2; kt++) {
    const ushort* Kr = Kc + (size_t)(kt * 16) * 64;
    kf[kt][0] = *(const short8*)Kr;
    kf[kt][1] = *(const short8*)(Kr + 32);
  }
  #pragma unroll
  for (int dt = 0; dt < 4; dt++)
    vf[dt] = *(const short8*)(Vc + (size_t)dt * 16 * 2048);

  for (int kb = 0; kb < 2048; kb += 32) {
    // issue next iteration's loads first (wraps harmlessly on last iter)
    const int kn = (kb + 32) & 2047;
    short8 nkf[2][2], nvf[4];
    #pragma unroll
    for (int kt = 0; kt < 2; kt++) {
      const ushort* Kr = Kc + (size_t)(kn + kt * 16) * 64;
      nkf[kt][0] = *(const short8*)Kr;
      nkf[kt][1] = *(const short8*)(Kr + 32);
    }
    #pragma unroll
    for (int dt = 0; dt < 4; dt++)
      nvf[dt] = *(const short8*)(Vc + (size_t)dt * 16 * 2048 + kn);

    #pragma unroll
    for (int qg = 0; qg < 4; qg++) {
      f32x4 s0 = (f32x4){0.f, 0.f, 0.f, 0.f};
      f32x4 s1 = (f32x4){0.f, 0.f, 0.f, 0.f};
      s0 = MFMA_BF16(kf[0][0], qa[qg][0], s0, 0, 0, 0);
      s0 = MFMA_BF16(kf[0][1], qa[qg][1], s0, 0, 0, 0);
      s1 = MFMA_BF16(kf[1][0], qa[qg][0], s1, 0, 0, 0);
      s1 = MFMA_BF16(kf[1][1], qa[qg][1], s1, 0, 0, 0);
      // scale folded into Q: p = exp2(s)
      float p0 = __builtin_amdgcn_exp2f(s0[0]);
      float p1 = __builtin_amdgcn_exp2f(s0[1]);
      float p2 = __builtin_amdgcn_exp2f(s0[2]);
      float p3 = __builtin_amdgcn_exp2f(s0[3]);
      float p4 = __builtin_amdgcn_exp2f(s1[0]);
      float p5 = __builtin_amdgcn_exp2f(s1[1]);
      float p6 = __builtin_amdgcn_exp2f(s1[2]);
      float p7 = __builtin_amdgcn_exp2f(s1[3]);
      l_part[qg] += (p0 + p1) + (p2 + p3) + (p4 + p5) + (p6 + p7);
      ushort(*P)[40] = P_lds[wave][qg];
      *(uint*)&P[col][quad * 4]          = pack_bf16_ru(p0, p1);
      *(uint*)&P[col][quad * 4 + 2]      = pack_bf16_ru(p2, p3);
      *(uint*)&P[col][16 + quad * 4]     = pack_bf16_ru(p4, p5);
      *(uint*)&P[col][16 + quad * 4 + 2] = pack_bf16_ru(p6, p7);
    }
    #pragma unroll
    for (int qg = 0; qg < 4; qg++) {
      short8 pf = *(const short8*)&P_lds[wave][qg][col][quad * 8];
      #pragma unroll
      for (int dt = 0; dt < 4; dt++)
        Ot[qg][dt] = MFMA_BF16(vf[dt], pf, Ot[qg][dt], 0, 0, 0);
    }
    #pragma unroll
    for (int kt = 0; kt < 2; kt++) { kf[kt][0] = nkf[kt][0]; kf[kt][1] = nkf[kt][1]; }
    #pragma unroll
    for (int dt = 0; dt < 4; dt++) vf[dt] = nvf[dt];
  }

  const int bb = bh >> 4, h = bh & 15;
  #pragma unroll
  for (int qg = 0; qg < 4; qg++) {
    float l = l_part[qg];
    l += __shfl_xor(l, 16);
    l += __shfl_xor(l, 32);
    float inv = __builtin_amdgcn_rcpf(l);
    const int q = qbase + qg * 16 + col;
    size_t base = ((size_t)(bb * 2048 + q)) * 1024 + h * 64;
    #pragma unroll
    for (int dt = 0; dt < 4; dt++) {
      ushort4 o;
      o.x = f2bf(Ot[qg][dt][0] * inv);
      o.y = f2bf(Ot[qg][dt][1] * inv);
      o.z = f2bf(Ot[qg][dt][2] * inv);
      o.w = f2bf(Ot[qg][dt][3] * inv);
      *(ushort4*)&ctx[base + dt * 16 + quad * 4] = o;
    }
  }
}

// ---------------- host ----------------
extern "C" void kernel_launch(void* const* d_in, const int* in_sizes, int n_in,
                              void* d_out, int out_size, void* d_ws, size_t ws_size,
                              hipStream_t stream) {
  const float* x     = (const float*)d_in[0];
  const float* Wq    = (const float*)d_in[1];
  const float* bq    = (const float*)d_in[2];
  const float* Wk    = (const float*)d_in[3];
  const float* bk    = (const float*)d_in[4];
  const float* Wv    = (const float*)d_in[5];
  const float* bv    = (const float*)d_in[6];
  const float* Wo    = (const float*)d_in[7];
  const float* bo    = (const float*)d_in[8];
  const float* W1    = (const float*)d_in[9];
  const float* b1    = (const float*)d_in[10];
  const float* W2    = (const float*)d_in[11];
  const float* b2    = (const float*)d_in[12];
  const float* ln1_g = (const float*)d_in[13];
  const float* ln1_b = (const float*)d_in[14];
  const float* ln2_g = (const float*)d_in[15];
  const float* ln2_b = (const float*)d_in[16];

  const size_t MB = 1ull << 20;
  char* ws = (char*)d_ws;
  ushort* Wqkv_b = (ushort*)(ws + 0 * MB);    // 6 MB  [3072,1024]
  ushort* Wo_b   = (ushort*)(ws + 6 * MB);    // 2 MB
  ushort* W1_b   = (ushort*)(ws + 8 * MB);    // 8 MB
  ushort* W2_b   = (ushort*)(ws + 16 * MB);   // 8 MB
  ushort* xn1    = (ushort*)(ws + 24 * MB);   // 16 MB
  ushort* Qb     = (ushort*)(ws + 40 * MB);   // 16 MB
  ushort* Kb     = (ushort*)(ws + 56 * MB);   // 16 MB
  ushort* Vt     = (ushort*)(ws + 72 * MB);   // 16 MB
  ushort* ctxb   = (ushort*)(ws + 88 * MB);   // 16 MB
  float*  x2     = (float*)(ws + 104 * MB);   // 32 MB
  ushort* xn2    = (ushort*)(ws + 136 * MB);  // 16 MB
  ushort* y1     = (ushort*)(ws + 152 * MB);  // 64 MB -> end 216 MB
  // bqkv aliases the start of y1: written by conv_all, consumed by the QKV GEMM,
  // clobbered only later by the W1 GEMM (same-stream ordering makes this safe).
  float*  bqkv   = (float*)(ws + 152 * MB);

  conv_all<<<12291, 256, 0, stream>>>(Wq, Wk, Wv, Wo, W1, W2, bq, bk, bv,
                                      Wqkv_b, Wo_b, W1_b, W2_b, bqkv);

  ln_kernel<<<8192, 256, 0, stream>>>(x, ln1_g, ln1_b, xn1);

  const float cs = 0.125f * 1.4426950408889634f;  // log2(e)/sqrt(64), folded into Q
  gemm_kernel<EPI_QKV><<<dim3(64, 24), 256, 0, stream>>>(
      xn1, Wqkv_b, bqkv, nullptr, Qb, Kb, Vt, 1024, 3072, cs);

  attn_kernel<<<512, 256, 0, stream>>>(Qb, Kb, Vt, ctxb);

  gemm_kernel<EPI_WO><<<dim3(64, 8), 256, 0, stream>>>(
      ctxb, Wo_b, bo, x, x2, nullptr, nullptr, 1024, 1024, 1.0f);

  ln_kernel<<<8192, 256, 0, stream>>>(x2, ln2_g, ln2_b, xn2);

  gemm_kernel<EPI_GELU><<<dim3(64, 32), 256, 0, stream>>>(
      xn2, W1_b, b1, nullptr, y1, nullptr, nullptr, 1024, 4096, 1.0f);
  gemm_kernel<EPI_OUT><<<dim3(64, 8), 256, 0, stream>>>(
      y1, W2_b, b2, x2, d_out, nullptr, nullptr, 4096, 1024, 1.0f);
}